// Round 12
// baseline (746.366 us; speedup 1.0000x reference)
//
#include <hip/hip_runtime.h>
#include <stdint.h>

#define SEQ      1024
#define NT       128
#define NBATCH   256
#define MID      512
#define WS_STRIDE 132        // 128 floats + kSum
#define NCHAIN   16          // chain blocks (16 batches each)

typedef float f32x4v __attribute__((ext_vector_type(4)));
using short8 = __attribute__((ext_vector_type(8))) short;
union B8 { uint4 u4; short8 s8; };

// tau(kt, 8g+e) = 16*(2kt+(e>>2)) + 4g + (e&3): D->cvt_pk words land exactly in
// B-fragment order, so B is recycled D (verified R4/R5/R6).
__device__ __forceinline__ int tau0(int kt, int g, int wi) {
    return 16 * (2 * kt + (wi >> 1)) + 4 * g + 2 * (wi & 1);
}

// blocks [0,16):    chain blocks: wave0 = fwd (steps 1..512), wave1 = bwd
//                   (v-space, steps 1023..514 + final beta_512 matvec)
// blocks [16,144):  score gathers (2 batches each)
__global__ __launch_bounds__(128, 1) void crf_chains(
    const float* __restrict__ emissions,   // [B, SEQ, NT]
    const float* __restrict__ transitions, // [NT, NT]
    const int*   __restrict__ tags,        // [B, SEQ]
    const float* __restrict__ mask,        // [B, SEQ]
    float* __restrict__ out,               // [1]
    float* __restrict__ ws)                // [2*256*132]
{
    const int blk = blockIdx.x;
    const int tid = threadIdx.x;

    if (blk >= NCHAIN) {
        // ---------------- score blocks ----------------
        int b    = (blk - NCHAIN) * 2 + (tid >> 6);
        int lane = tid & 63;
        const float* emb = emissions + (size_t)b * SEQ * NT;
        const int*   tgb = tags + (size_t)b * SEQ;
        const float* mkb = mask + (size_t)b * SEQ;
        float sc = 0.f;
        for (int t = lane; t < SEQ; t += 64) {
            int   tg = tgb[t];
            float mt = mkb[t];
            sc += emb[t * NT + tg] * mt;
            if (t >= 1) sc += transitions[tgb[t - 1] * NT + tg] * mt;
        }
#pragma unroll
        for (int o = 32; o > 0; o >>= 1) sc += __shfl_down(sc, o, 64);
        if (lane == 0) atomicAdd(out, -sc * (1.0f / NBATCH));
        return;
    }

    // ---------------- chain block: 16 batches, 2 independent waves ----------------
    __shared__ __align__(16) uint4 A_lds[2][32][64];   // 64 KB: [dir][kt*8+m][lane]

    const int wid   = tid >> 6;    // 0 = fwd, 1 = bwd
    const int lane  = tid & 63;
    const int g     = lane >> 4;   // 0..3
    const int c     = lane & 15;   // batch column
    const int bbase = blk * 16;
    const int dir   = wid;

    // A init (own wave's half only; wave reads only what it wrote -> no barrier
    // strictly needed, keep one for safety). fwd: A = expT^T ; bwd: A = expT.
#pragma unroll
    for (int m = 0; m < 8; ++m) {
        int jj = 16 * m + c;
#pragma unroll
        for (int kt = 0; kt < 4; ++kt) {
            uint32_t w[4];
#pragma unroll
            for (int wi = 0; wi < 4; ++wi) {
                int T0 = tau0(kt, g, wi);
                float f0 = __expf(dir ? transitions[jj * NT + T0]
                                      : transitions[T0 * NT + jj]);
                float f1 = __expf(dir ? transitions[jj * NT + T0 + 1]
                                      : transitions[(T0 + 1) * NT + jj]);
                asm("v_cvt_pk_bf16_f32 %0, %1, %2" : "=v"(w[wi]) : "v"(f0), "v"(f1));
            }
            A_lds[dir][kt * 8 + m][lane] = make_uint4(w[0], w[1], w[2], w[3]);
        }
    }
    __syncthreads();

    const float* ebc = emissions + (size_t)(bbase + c) * SEQ * NT;
    const float* mbc = mask + (size_t)(bbase + c) * SEQ;

    // init B: fwd = exp(E_0) = gamma_0 ; bwd = exp(E_1023) = v_1023
    B8 Bf[4];
    {
        const int t0 = dir ? (SEQ - 1) : 0;
#pragma unroll
        for (int kt = 0; kt < 4; ++kt) {
            uint32_t w[4];
#pragma unroll
            for (int wi = 0; wi < 4; ++wi) {
                int T0 = tau0(kt, g, wi);
                float2 ld = *(const float2*)(ebc + (size_t)t0 * NT + T0);
                float f0 = __expf(ld.x), f1 = __expf(ld.y);
                asm("v_cvt_pk_bf16_f32 %0, %1, %2" : "=v"(w[wi]) : "v"(f0), "v"(f1));
            }
            Bf[kt].u4 = make_uint4(w[0], w[1], w[2], w[3]);
        }
    }

    // first E/M prefetch: fwd step0 uses E_1/mask_1; bwd step0 uses E_1022/mask_1023
    float4 E[8];
    {
        const int et = dir ? (SEQ - 2) : 1;
#pragma unroll
        for (int m = 0; m < 8; ++m)
            E[m] = *(const float4*)(ebc + (size_t)et * NT + 4 * g + 16 * m);
    }
    float Mreg = mbc[dir ? (SEQ - 1) : 1];

    int   kSum = 0;
    const int NS = dir ? (MID - 2) : MID;   // bwd: 510 normal steps, fwd: 512
    const f32x4v zero4 = {0.f, 0.f, 0.f, 0.f};
    const uint4* Ab0 = &A_lds[dir][0][0];

    for (int s = 0; s < NS; ++s) {
        // opaque zero: A reads depend on it -> can't be hoisted out (spill trap)
        uint32_t z = 0;
        asm volatile("" : "+v"(z));
        const uint4* Ab = Ab0 + z;

        // rescale (every 4th step) from anchor tag0 of batch c, exact pow-2
        const bool resc = ((s & 3) == 3);
        float rcf = 1.0f; int kk = 0;
        if (resc) {
            int v  = __builtin_amdgcn_ds_bpermute(c << 2, (int)Bf[0].u4.x);
            int eb = (v >> 7) & 0xff;
            kk  = eb - 127;
            rcf = __uint_as_float((uint32_t)(254 - eb) << 23);
        }

        // 32 MFMA, kt-major (8 independent chains), A streamed from LDS
        f32x4v acc[8];
        {
            B8 a[8];
#pragma unroll
            for (int m = 0; m < 8; ++m) a[m].u4 = Ab[m * 64 + lane];
#pragma unroll
            for (int m = 0; m < 8; ++m)
                acc[m] = __builtin_amdgcn_mfma_f32_16x16x32_bf16(a[m].s8, Bf[0].s8, zero4, 0, 0, 0);
        }
#pragma unroll
        for (int kt = 1; kt < 4; ++kt) {
            B8 a[8];
#pragma unroll
            for (int m = 0; m < 8; ++m) a[m].u4 = Ab[(kt * 8 + m) * 64 + lane];
#pragma unroll
            for (int m = 0; m < 8; ++m)
                acc[m] = __builtin_amdgcn_mfma_f32_16x16x32_bf16(a[m].s8, Bf[kt].s8, acc[m], 0, 0, 0);
        }

        const float mt  = Mreg;
        const bool  upd = (mt != 0.0f);
        if (resc && upd) kSum += kk;

        // epilogue: state_new = D * exp(E) (* rc) -> bf16 pairs -> Bn
        uint32_t pk[8][2];
#pragma unroll
        for (int m = 0; m < 8; ++m) {
            float4 e = E[m];
            float e0 = __expf(e.x), e1 = __expf(e.y);
            float e2 = __expf(e.z), e3 = __expf(e.w);
            if (resc) { e0 *= rcf; e1 *= rcf; e2 *= rcf; e3 *= rcf; }
            float x0 = acc[m][0] * e0, x1 = acc[m][1] * e1;
            float x2 = acc[m][2] * e2, x3 = acc[m][3] * e3;
            asm("v_cvt_pk_bf16_f32 %0, %1, %2" : "=v"(pk[m][0]) : "v"(x0), "v"(x1));
            asm("v_cvt_pk_bf16_f32 %0, %1, %2" : "=v"(pk[m][1]) : "v"(x2), "v"(x3));
        }
        B8 Bn[4];
#pragma unroll
        for (int kt = 0; kt < 4; ++kt)
            Bn[kt].u4 = make_uint4(pk[2*kt][0], pk[2*kt][1], pk[2*kt+1][0], pk[2*kt+1][1]);

        if (dir == 0) {
            // fwd masked: keep old gamma (exact reference semantics)
#pragma unroll
            for (int kt = 0; kt < 4; ++kt)
                if (upd) Bf[kt].u4 = Bn[kt].u4;
        } else {
            if (__builtin_expect(__all((int)upd), 1)) {
#pragma unroll
                for (int kt = 0; kt < 4; ++kt) Bf[kt].u4 = Bn[kt].u4;
            } else {
                // cold: masked bwd step: v_new = v_old * exp(E_new - E_old)
                const int tm = SEQ - 1 - s;   // e_old time
                const int te = SEQ - 2 - s;   // e_new time (current step)
                float4 Eo[8], En2[8];
#pragma unroll
                for (int m = 0; m < 8; ++m) {
                    Eo[m]  = *(const float4*)(ebc + (size_t)tm * NT + 4 * g + 16 * m);
                    En2[m] = *(const float4*)(ebc + (size_t)te * NT + 4 * g + 16 * m);
                }
#pragma unroll
                for (int kt = 0; kt < 4; ++kt) {
                    uint32_t bw[4] = {Bf[kt].u4.x, Bf[kt].u4.y, Bf[kt].u4.z, Bf[kt].u4.w};
                    uint32_t nw[4] = {Bn[kt].u4.x, Bn[kt].u4.y, Bn[kt].u4.z, Bn[kt].u4.w};
                    uint32_t ow[4];
#pragma unroll
                    for (int wi = 0; wi < 4; ++wi) {
                        int mp = 2 * kt + (wi >> 1), j0 = 2 * (wi & 1);
                        const float* en = (const float*)&En2[mp];
                        const float* eo = (const float*)&Eo[mp];
                        float r0 = __expf(en[j0]     - eo[j0]);
                        float r1 = __expf(en[j0 + 1] - eo[j0 + 1]);
                        float lo = __uint_as_float(bw[wi] << 16) * r0;
                        float hi = __uint_as_float(bw[wi] & 0xffff0000u) * r1;
                        uint32_t cw;
                        asm("v_cvt_pk_bf16_f32 %0, %1, %2" : "=v"(cw) : "v"(lo), "v"(hi));
                        ow[wi] = upd ? nw[wi] : cw;
                    }
                    Bf[kt].u4 = make_uint4(ow[0], ow[1], ow[2], ow[3]);
                }
            }
        }

        // prefetch next step's E and mask (fwd: t=s+2 ; bwd: t=1021-s)
        {
            const int tn  = dir ? (SEQ - 3 - s) : (2 + s);
            const int tmn = dir ? (SEQ - 2 - s) : (2 + s);
#pragma unroll
            for (int m = 0; m < 8; ++m)
                E[m] = *(const float4*)(ebc + (size_t)tn * NT + 4 * g + 16 * m);
            Mreg = mbc[tmn];
        }
    }

    float* wsb = ws + (size_t)(dir * NBATCH + bbase + c) * WS_STRIDE;
    if (dir == 0) {
        // alpha_512 (bf16, scaled 2^kSum) -> ws
#pragma unroll
        for (int kt = 0; kt < 4; ++kt) {
            uint32_t bw[4] = {Bf[kt].u4.x, Bf[kt].u4.y, Bf[kt].u4.z, Bf[kt].u4.w};
#pragma unroll
            for (int wi = 0; wi < 4; ++wi) {
                int T0 = tau0(kt, g, wi);
                wsb[T0]     = __uint_as_float(bw[wi] << 16);
                wsb[T0 + 1] = __uint_as_float(bw[wi] & 0xffff0000u);
            }
        }
        if (g == 0) wsb[128] = (float)kSum;
    } else {
        // final matvec (no emission): beta_512 = expT * v_513, f32
        uint32_t z = 0;
        asm volatile("" : "+v"(z));
        const uint4* Ab = Ab0 + z;
        f32x4v acc[8];
        {
            B8 a[8];
#pragma unroll
            for (int m = 0; m < 8; ++m) a[m].u4 = Ab[m * 64 + lane];
#pragma unroll
            for (int m = 0; m < 8; ++m)
                acc[m] = __builtin_amdgcn_mfma_f32_16x16x32_bf16(a[m].s8, Bf[0].s8, zero4, 0, 0, 0);
        }
#pragma unroll
        for (int kt = 1; kt < 4; ++kt) {
            B8 a[8];
#pragma unroll
            for (int m = 0; m < 8; ++m) a[m].u4 = Ab[(kt * 8 + m) * 64 + lane];
#pragma unroll
            for (int m = 0; m < 8; ++m)
                acc[m] = __builtin_amdgcn_mfma_f32_16x16x32_bf16(a[m].s8, Bf[kt].s8, acc[m], 0, 0, 0);
        }
#pragma unroll
        for (int m = 0; m < 8; ++m)
            *(f32x4v*)(wsb + 16 * m + 4 * g) = acc[m];
        if (g == 0) wsb[128] = (float)kSum;
    }
}

// Z = sum_i alpha_MID[i] * beta_MID[i] * 2^(kF+kB)
__global__ __launch_bounds__(64) void crf_combine(
    const float* __restrict__ ws, float* __restrict__ out)
{
    int b    = blockIdx.x;
    int lane = threadIdx.x;
    const float* af = ws + (size_t)b * WS_STRIDE;
    const float* bf = ws + (size_t)(NBATCH + b) * WS_STRIDE;
    float d = af[lane] * bf[lane] + af[lane + 64] * bf[lane + 64];
#pragma unroll
    for (int o = 32; o > 0; o >>= 1) d += __shfl_down(d, o, 64);
    if (lane == 0) {
        float logZ = __logf(d) + (af[128] + bf[128]) * 0.69314718055994531f;
        atomicAdd(out, logZ * (1.0f / NBATCH));
    }
}

extern "C" void kernel_launch(void* const* d_in, const int* in_sizes, int n_in,
                              void* d_out, int out_size, void* d_ws, size_t ws_size,
                              hipStream_t stream) {
    const float* emissions   = (const float*)d_in[0];
    const float* transitions = (const float*)d_in[1];
    const int*   tags        = (const int*)d_in[2];
    const float* mask        = (const float*)d_in[3];
    float*       out         = (float*)d_out;
    float*       ws          = (float*)d_ws;

    hipMemsetAsync(out, 0, sizeof(float), stream);
    crf_chains<<<NCHAIN + NBATCH / 2, 128, 0, stream>>>(
        emissions, transitions, tags, mask, out, ws);
    crf_combine<<<NBATCH, 64, 0, stream>>>(ws, out);
}

// Round 13
// 252.663 us; speedup vs baseline: 2.9540x; 2.9540x over previous
//
#include <hip/hip_runtime.h>
#include <stdint.h>

#define SEQ      1024
#define NT       128
#define NBATCH   256
#define MID      512
#define WS_STRIDE 132       // 128 floats + kSum

// bf16 pair dot with f32 accumulate
#if defined(__has_builtin)
#if __has_builtin(__builtin_amdgcn_fdot2_f32_bf16)
#define HAVE_BF16_DOT2 1
#endif
#endif

#ifdef HAVE_BF16_DOT2
typedef __bf16 v2bf __attribute__((ext_vector_type(2)));
#define DOT2ACC(a, su, wu) \
    a = __builtin_amdgcn_fdot2_f32_bf16(__builtin_bit_cast(v2bf, (su)), \
                                        __builtin_bit_cast(v2bf, (wu)), a, false)
#else
#define DOT2ACC(a, su, wu) { \
    a = fmaf(__uint_as_float((wu) << 16),         __uint_as_float((su) << 16),         a); \
    a = fmaf(__uint_as_float((wu) & 0xffff0000u), __uint_as_float((su) & 0xffff0000u), a); }
#endif

// 16 NAMED u32 weight regs (bf16 pairs) = 16 VGPRs -> total live ~55, fits the
// allocator's 64-reg occupancy band (the R1..R11 spill lesson).
#define RALL(X) X(0) X(1) X(2) X(3) X(4) X(5) X(6) X(7) \
                X(8) X(9) X(10) X(11) X(12) X(13) X(14) X(15)
#define DECLW(k) uint32_t W##k;
#define INITW(k) { \
    float f0_ = __expf(wbase[(2 * (k)    ) * wstr]); \
    float f1_ = __expf(wbase[(2 * (k) + 1) * wstr]); \
    asm("v_cvt_pk_bf16_f32 %0, %1, %2" : "=v"(W##k) : "v"(f0_), "v"(f1_)); }
#define PINW(k)  asm volatile("" : "+v"(W##k));

#define MQ(c, k0, k1, k2, k3) { \
    uint4 u_ = *(const uint4*)(gp + 4 * (c)); \
    DOT2ACC(a0, u_.x, W##k0); \
    DOT2ACC(a1, u_.y, W##k1); \
    DOT2ACC(a2, u_.z, W##k2); \
    DOT2ACC(a3, u_.w, W##k3); }

// 32-tag quarter dot (16 dot2) + cross-q combine (partners = adjacent lanes)
#define MATVEC32(S_) { \
    float a0 = 0.f, a1 = 0.f, a2 = 0.f, a3 = 0.f; \
    MQ(0,0,1,2,3) MQ(1,4,5,6,7) MQ(2,8,9,10,11) MQ(3,12,13,14,15) \
    S_ = (a0 + a1) + (a2 + a3); \
    S_ += __shfl_xor(S_, 1, 64); \
    S_ += __shfl_xor(S_, 2, 64); }

#define BF16_STORE(buf_, val_) { \
    uint32_t pk_; \
    asm("v_cvt_pk_bf16_f32 %0, %1, %2" : "=v"(pk_) : "v"(val_), "v"(val_)); \
    ((unsigned short*)(buf_))[jt] = (unsigned short)(pk_ & 0xffffu); }

// blocks [0,256):    forward chains (batch = blk, steps 1..512)
// blocks [256,512):  backward chains (batch = blk-256, steps 1023..513)
// blocks [512,544):  score gathers (8 batches each)
__global__ __launch_bounds__(512) void crf_chains(
    const float* __restrict__ emissions,   // [B, SEQ, NT]
    const float* __restrict__ transitions, // [NT, NT]
    const int*   __restrict__ tags,        // [B, SEQ]
    const float* __restrict__ mask,        // [B, SEQ]
    float* __restrict__ out,               // [1]
    float* __restrict__ ws)                // [2*256*132]
{
    const int blk = blockIdx.x;
    const int tid = threadIdx.x;

    if (blk >= 2 * NBATCH) {
        // ---------------- score blocks ----------------
        int b    = (blk - 2 * NBATCH) * 8 + (tid >> 6);
        int lane = tid & 63;
        const float* emb = emissions + (size_t)b * SEQ * NT;
        const int*   tgb = tags + (size_t)b * SEQ;
        const float* mkb = mask + (size_t)b * SEQ;
        float sc = 0.f;
        for (int t = lane; t < SEQ; t += 64) {
            int   tg = tgb[t];
            float mt = mkb[t];
            sc += emb[t * NT + tg] * mt;
            if (t >= 1) sc += transitions[tgb[t - 1] * NT + tg] * mt;
        }
#pragma unroll
        for (int o = 32; o > 0; o >>= 1) sc += __shfl_down(sc, o, 64);
        if (lane == 0) atomicAdd(out, -sc * (1.0f / NBATCH));
        return;
    }

    // ---------------- chain block ----------------
    // state = 64 u32 bf16 pairs (tags 2i, 2i+1), double-buffered
    __shared__ __align__(16) uint32_t buf[2][NT / 2];

    const int jt = tid >> 2;   // owned output tag 0..127
    const int q  = tid & 3;    // predecessor quarter (32 tags)

    const bool fwd = (blk < NBATCH);
    const int  b   = fwd ? blk : blk - NBATCH;

    const float* emb = emissions + (size_t)b * SEQ * NT;
    const float* mkb = mask + (size_t)b * SEQ;

    // fwd: expT[32q+2k][jt] (col jt, stride NT); bwd: expT[jt][32q+2k] (row, contig)
    const float* wbase = fwd ? (transitions + (size_t)(32 * q) * NT + jt)
                             : (transitions + (size_t)jt * NT + 32 * q);
    const int    wstr  = fwd ? NT : 1;

    RALL(DECLW)
    RALL(INITW)
    RALL(PINW)

    int   kSum = 0, p = 0;
    float gcur = 0.f, beta = 1.0f;
    float E0, E1, M0, M1;

    if (fwd) {
        gcur = __expf(emb[jt]);
        if (q == 0) BF16_STORE(buf[0], gcur);
        E0 = emb[1 * NT + jt];  E1 = emb[2 * NT + jt];
        M0 = mkb[1];            M1 = mkb[2];
    } else {
        float w0 = __expf(emb[(size_t)(SEQ - 1) * NT + jt]);   // w_1023 (beta=1)
        if (q == 0) BF16_STORE(buf[0], w0);
        E0 = emb[(size_t)(SEQ - 2) * NT + jt];
        E1 = emb[(size_t)(SEQ - 3) * NT + jt];
        M0 = mkb[SEQ - 1];      M1 = mkb[SEQ - 2];
    }
    __syncthreads();

    if (fwd) {
        // ---------- forward: 512 steps, t = 1+s ----------
        for (int s = 0; s < MID; ++s) {
            float En = emb[(size_t)(3 + s) * NT + jt];   // <= 514
            float Mn = mkb[3 + s];
            if (M0 != 0.0f) {
                const uint32_t* gp = buf[p] + 16 * q;
                uint32_t anchor = buf[p][0];
                float sres;
                MATVEC32(sres);
                int   e  = (int)((anchor >> 7) & 0xff);  // bf16 exp of tag0
                float rc = __uint_as_float((uint32_t)(254 - e) << 23);
                kSum += e - 127;
                if (q == 0) {
                    gcur = sres * rc * __expf(E0);
                    BF16_STORE(buf[p ^ 1], gcur);
                }
                p ^= 1;
            }
            __syncthreads();
            E0 = E1; E1 = En; M0 = M1; M1 = Mn;
        }
        float* wsb = ws + (size_t)b * WS_STRIDE;
        if (q == 0)  wsb[jt] = gcur;          // alpha_512 (pow2-scaled)
        if (tid == 0) wsb[128] = (float)kSum;
    } else {
        // ---------- backward: 511 steps, t = 1023-s; buf holds w = beta.*expE ----------
        for (int s = 0; s < MID - 1; ++s) {
            float En = emb[(size_t)(SEQ - 4 - s) * NT + jt];  // >= 510
            float Mn = mkb[SEQ - 3 - s];
            {
                const uint32_t* gp = buf[p] + 16 * q;
                uint32_t anchor = buf[p][0];
                float sres;
                MATVEC32(sres);
                int   e  = (int)((anchor >> 7) & 0xff);
                float rc = __uint_as_float((uint32_t)(254 - e) << 23);
                kSum += e - 127;
                float bn = (M0 != 0.0f) ? sres * rc : beta * rc;
                beta = bn;
                if (q == 0) {
                    float g = bn * __expf(E0);   // w_{t-1}
                    BF16_STORE(buf[p ^ 1], g);
                }
                p ^= 1;
            }
            __syncthreads();
            E0 = E1; E1 = En; M0 = M1; M1 = Mn;
        }
        float* wsb = ws + (size_t)(NBATCH + b) * WS_STRIDE;
        if (q == 0)  wsb[jt] = beta;          // beta_512 (pow2-scaled)
        if (tid == 0) wsb[128] = (float)kSum;
    }
}

// Z = sum_i alpha_MID[i] * beta_MID[i] * 2^(kF+kB)
__global__ __launch_bounds__(64) void crf_combine(
    const float* __restrict__ ws, float* __restrict__ out)
{
    int b    = blockIdx.x;
    int lane = threadIdx.x;
    const float* af = ws + (size_t)b * WS_STRIDE;
    const float* bf = ws + (size_t)(NBATCH + b) * WS_STRIDE;
    float d = af[lane] * bf[lane] + af[lane + 64] * bf[lane + 64];
#pragma unroll
    for (int o = 32; o > 0; o >>= 1) d += __shfl_down(d, o, 64);
    if (lane == 0) {
        float logZ = __logf(d) + (af[128] + bf[128]) * 0.69314718055994531f;
        atomicAdd(out, logZ * (1.0f / NBATCH));
    }
}

extern "C" void kernel_launch(void* const* d_in, const int* in_sizes, int n_in,
                              void* d_out, int out_size, void* d_ws, size_t ws_size,
                              hipStream_t stream) {
    const float* emissions   = (const float*)d_in[0];
    const float* transitions = (const float*)d_in[1];
    const int*   tags        = (const int*)d_in[2];
    const float* mask        = (const float*)d_in[3];
    float*       out         = (float*)d_out;
    float*       ws          = (float*)d_ws;

    hipMemsetAsync(out, 0, sizeof(float), stream);
    crf_chains<<<2 * NBATCH + 32, 512, 0, stream>>>(
        emissions, transitions, tags, mask, out, ws);
    crf_combine<<<NBATCH, 64, 0, stream>>>(ws, out);
}